// Round 11
// baseline (247.611 us; speedup 1.0000x reference)
//
#include <hip/hip_runtime.h>
#include <hip/hip_bf16.h>
#include <stdint.h>

// B=4, C=512, H=W=64 -> N=4096. Channel-first x [B,C,N].
#define C_DIM 512
#define N_DIM 4096
#define B_DIM 4

typedef __bf16 bf16x8 __attribute__((ext_vector_type(8)));
typedef float f32x4 __attribute__((ext_vector_type(4)));
#define AS1 __attribute__((address_space(1)))
#define AS3 __attribute__((address_space(3)))

static __device__ __forceinline__ unsigned short f2bf(float x) {
  unsigned u = __float_as_uint(x);
  unsigned r = (u + 0x7fffu + ((u >> 16) & 1u)) >> 16;
  return (unsigned short)r;
}
static __device__ __forceinline__ unsigned char f2fp8(float x) {
  return (unsigned char)__builtin_amdgcn_cvt_pk_fp8_f32(x, x, 0, false);
}

__global__ __launch_bounds__(256) void cvt_weights(
    const float* __restrict__ w0, const float* __restrict__ w1,
    const float* __restrict__ w2, const float* __restrict__ w3,
    unsigned short* __restrict__ o0, unsigned short* __restrict__ o1,
    unsigned short* __restrict__ o2, unsigned short* __restrict__ o3) {
  int i = blockIdx.x * blockDim.x + threadIdx.x;
  if (i < C_DIM * C_DIM) {
    o0[i] = f2bf(w0[i]); o1[i] = f2bf(w1[i]);
    o2[i] = f2bf(w2[i]); o3[i] = f2bf(w3[i]);
  }
}

// x [B,C,N] f32 -> Xt [B,N,C] bf16
__global__ __launch_bounds__(256) void transpose_x(
    const float* __restrict__ x, unsigned short* __restrict__ Xt) {
  __shared__ float t[32][33];
  const int b = blockIdx.z;
  const float* xb = x + (size_t)b * C_DIM * N_DIM;
  unsigned short* xtb = Xt + (size_t)b * N_DIM * C_DIM;
  const int n0 = blockIdx.x * 32, c0 = blockIdx.y * 32;
  const int tx = threadIdx.x, ty = threadIdx.y;
  #pragma unroll
  for (int i = ty; i < 32; i += 8)
    t[i][tx] = xb[(size_t)(c0 + i) * N_DIM + n0 + tx];
  __syncthreads();
  #pragma unroll
  for (int i = ty; i < 32; i += 8)
    xtb[(size_t)(n0 + i) * C_DIM + c0 + tx] = f2bf(t[tx][i]);
}

__global__ __launch_bounds__(256) void zero_buf(float* __restrict__ p, int n) {
  int i = blockIdx.x * 256 + threadIdx.x;
  if (i < n) p[i] = 0.f;
}

// ---------------- 128^2-tile 2-phase NT GEMM body (bf16 inputs) ------------
// C[i,j] = sum_k A[i,k]B[j,k]; BIAS: 0 none, 1 +bias[col].
// OUT8: 1 -> fp8 e4m3 output, 0 -> bf16 output.
template<int BIAS, int OUT8>
__device__ __forceinline__ void gemm128_body(
    unsigned short* As, unsigned short* Bs,
    const unsigned short* __restrict__ A, const unsigned short* __restrict__ B,
    void* __restrict__ Cv, int K, int ldc,
    const float* __restrict__ bias, int bx, int by) {
  const int tid = threadIdx.x;
  const int wid = tid >> 6, lane = tid & 63;
  const int wm = (wid >> 1) * 64, wn = (wid & 1) * 64;
  f32x4 acc[4][4] = {};
  const size_t rowA0 = (size_t)bx * 128;
  const size_t rowB0 = (size_t)by * 128;
  const int sgrp = wid * 2;
  const int r0 = (sgrp * 64 + lane) >> 2;
  const int r1 = ((sgrp + 1) * 64 + lane) >> 2;
  const int cc = ((lane & 3) ^ ((lane >> 3) & 3)) * 8;
  const int lr = lane & 15;
  const int koff = (((lane >> 4) ^ ((lr >> 1) & 3))) * 8;

  for (int k0 = 0; k0 < K; k0 += 32) {
    __syncthreads();
    __builtin_amdgcn_global_load_lds(
        (const AS1 void*)(A + (rowA0 + r0) * K + k0 + cc),
        (AS3 void*)(As + sgrp * 512), 16, 0, 0);
    __builtin_amdgcn_global_load_lds(
        (const AS1 void*)(A + (rowA0 + r1) * K + k0 + cc),
        (AS3 void*)(As + (sgrp + 1) * 512), 16, 0, 0);
    __builtin_amdgcn_global_load_lds(
        (const AS1 void*)(B + (rowB0 + r0) * K + k0 + cc),
        (AS3 void*)(Bs + sgrp * 512), 16, 0, 0);
    __builtin_amdgcn_global_load_lds(
        (const AS1 void*)(B + (rowB0 + r1) * K + k0 + cc),
        (AS3 void*)(Bs + (sgrp + 1) * 512), 16, 0, 0);
    __syncthreads();
    bf16x8 af[4], bf[4];
    #pragma unroll
    for (int m = 0; m < 4; ++m)
      af[m] = *reinterpret_cast<const bf16x8*>(&As[(wm + m * 16 + lr) * 32 + koff]);
    #pragma unroll
    for (int n = 0; n < 4; ++n)
      bf[n] = *reinterpret_cast<const bf16x8*>(&Bs[(wn + n * 16 + lr) * 32 + koff]);
    #pragma unroll
    for (int m = 0; m < 4; ++m)
      #pragma unroll
      for (int n = 0; n < 4; ++n)
        acc[m][n] = __builtin_amdgcn_mfma_f32_16x16x32_bf16(af[m], bf[n], acc[m][n], 0, 0, 0);
  }

  const int rg = (lane >> 4) * 4;
  #pragma unroll
  for (int m = 0; m < 4; ++m) {
    #pragma unroll
    for (int n = 0; n < 4; ++n) {
      const int col = (int)rowB0 + wn + n * 16 + lr;
      #pragma unroll
      for (int r = 0; r < 4; ++r) {
        int row = (int)rowA0 + wm + m * 16 + rg + r;
        float v = acc[m][n][r];
        if (BIAS == 1) v += bias[col];
        if (OUT8)
          ((unsigned char*)Cv)[(size_t)row * ldc + col] = f2fp8(v);
        else
          ((unsigned short*)Cv)[(size_t)row * ldc + col] = f2bf(v);
      }
    }
  }
}

// merged Q,K,V projections: grid (32, 4, 12); z = wsel + 3*batch
// Q,K written as fp8 e4m3; V as bf16 (consumed by gemm_pvt).
__global__ __launch_bounds__(256, 2) void gemm_qkv(
    const unsigned short* __restrict__ Xt,
    const unsigned short* __restrict__ Wq, const unsigned short* __restrict__ Wk,
    const unsigned short* __restrict__ Wv,
    const float* __restrict__ bq, const float* __restrict__ bk,
    const float* __restrict__ bv,
    unsigned char* __restrict__ Qb, unsigned char* __restrict__ Kb,
    unsigned short* __restrict__ Vb) {
  __shared__ unsigned short As[4096], Bs[4096];
  const long NCe = (long)N_DIM * C_DIM;
  const int z = blockIdx.z;
  const int wsel = z % 3, bat = z / 3;
  const unsigned short* Xz = Xt + (size_t)bat * NCe;
  if (wsel == 0) {
    gemm128_body<1, 1>(As, Bs, Xz, Wq, Qb + (size_t)bat * NCe, C_DIM, C_DIM,
                       bq, blockIdx.x, blockIdx.y);
  } else if (wsel == 1) {
    gemm128_body<1, 1>(As, Bs, Xz, Wk, Kb + (size_t)bat * NCe, C_DIM, C_DIM,
                       bk, blockIdx.x, blockIdx.y);
  } else {
    gemm128_body<1, 0>(As, Bs, Xz, Wv, Vb + (size_t)bat * NCe, C_DIM, C_DIM,
                       bv, blockIdx.x, blockIdx.y);
  }
}

// PVt[o,j] = sum_c Wp[o,c] V[j,c] -> fp8; grid (4, 32, 4)
__global__ __launch_bounds__(256, 2) void gemm_pvt(
    const unsigned short* __restrict__ Wp, const unsigned short* __restrict__ Vb,
    unsigned char* __restrict__ PVt) {
  __shared__ unsigned short As[4096], Bs[4096];
  const long NCe = (long)N_DIM * C_DIM;
  const long PVe = (long)C_DIM * N_DIM;
  const int z = blockIdx.z;
  gemm128_body<0, 1>(As, Bs, Wp, Vb + (size_t)z * NCe, PVt + (size_t)z * PVe,
                     C_DIM, N_DIM, nullptr, blockIdx.x, blockIdx.y);
}

// ---------------- pipelined NT fp8 GEMM (R10 sync structure) ----------------
// A-tile MT=MF*32 rows x BK=64 (fp8: 64 B/row); B-tile 256 x 64. 8 waves
// (2M x 4N), acc[MF][4], mfma_f32_16x16x32_fp8_fp8 (A/B frag = 8 B/lane ->
// ds_read_b64, LDS bytes HALVED vs bf16 -> the measured 27% MfmaUtil ceiling
// [620cy MFMA vs ~2300cy ds_read] doubles). LDS 64/48 KB -> 2 blocks/CU.
// Per tile: BODY; BAR; STAGE(P,k+2); vmcnt(LOADS); BAR  (race-free per R6).
// Swizzle: rows are 4x16B slots; phys slot p of row r holds global slot
// p ^ (r&3); staged via pre-swizzled global source, read with slot ^ (lr&3).
// MODE 0: store fp8 exp(scale*acc); row-sums (f32, pre-rounding) -> atomicAdd
//         denom[row].
// MODE 1: store f32 acc/denom[col] + bias[row] + resid  (final output).
#define BAR() do { asm volatile("" ::: "memory"); __builtin_amdgcn_s_barrier(); \
                   asm volatile("" ::: "memory"); } while (0)

template<int MF, int MODE, int GX, int GY>
__global__ __launch_bounds__(512, 2) void gemm_p(
    const unsigned char* __restrict__ A, long sA,
    const unsigned char* __restrict__ B, long sB,
    void* __restrict__ Cp, long sC,
    int K, int lda, int ldb, int ldc, float scale,
    const float* __restrict__ bias,
    float* __restrict__ denom, long sDen,
    const float* __restrict__ resid, long sR) {
  constexpr int MT     = MF * 32;
  constexpr int ABUF   = MT * 64;       // BYTES per A parity buffer
  constexpr int ALOADS = MT / 128;      // 8KB gload sweeps per A tile
  __shared__ unsigned char lds[2 * ABUF + 32768];
  unsigned char* Ab = lds;
  unsigned char* Bb = lds + 2 * ABUF;

  // XCD-aware bijective block swizzle (nwg % 8 == 0 at all call sites)
  int flat = blockIdx.x + GX * (blockIdx.y + GY * blockIdx.z);
  const int nwg = GX * GY * gridDim.z;
  flat = (flat & 7) * (nwg >> 3) + (flat >> 3);
  const int bx = flat & (GX - 1);
  const int by = (flat / GX) & (GY - 1);
  const int z  = flat / (GX * GY);

  const unsigned char* Ag = A + (size_t)z * sA + (size_t)bx * MT * lda;
  const unsigned char* Bg = B + (size_t)z * sB + (size_t)by * 256 * ldb;
  const int tid = threadIdx.x;
  const int wid = tid >> 6, lane = tid & 63;
  const int wr = wid >> 2, wc = wid & 3;
  const int lr = lane & 15, q = lane >> 4;

  // staging: 4 threads/row (64 B); phys slot lane&3 carries global slot
  // (lane&3)^(row&3), row&3 = (lane>>2)&3
  const int ssl = (lane & 3) ^ ((lane >> 2) & 3);
  int agv[ALOADS], bgv[2];
  #pragma unroll
  for (int i = 0; i < ALOADS; ++i)
    agv[i] = (i * 128 + wid * 16 + (lane >> 2)) * lda + ssl * 16;
  #pragma unroll
  for (int i = 0; i < 2; ++i)
    bgv[i] = (i * 128 + wid * 16 + (lane >> 2)) * ldb + ssl * 16;

  auto STAGE = [&](int P, int tt) {  // P literal at call sites
    const int t64 = tt << 6;  // 64 bytes per K-tile
    #pragma unroll
    for (int i = 0; i < ALOADS; ++i)
      __builtin_amdgcn_global_load_lds(
          (const AS1 void*)(Ag + agv[i] + t64),
          (AS3 void*)(Ab + P * ABUF + i * 8192 + wid * 1024), 16, 0, 0);
    #pragma unroll
    for (int i = 0; i < 2; ++i)
      __builtin_amdgcn_global_load_lds(
          (const AS1 void*)(Bg + bgv[i] + t64),
          (AS3 void*)(Bb + P * 16384 + i * 8192 + wid * 1024), 16, 0, 0);
  };

  // reads: frag (row R, kk): 8 B at byte k = q*8 + kk*32; slot s=(q>>1)+kk*2,
  // in-slot (q&1)*8; phys slot = s ^ (lr&3)  [R&3 == lr&3 for frag rows]
  const int s0b = ((q >> 1) ^ (lr & 3)) * 16 + (q & 1) * 8;
  const unsigned char* a0 = Ab + (wr * (MT / 2) + lr) * 64 + s0b;
  const unsigned char* a1 = Ab + (wr * (MT / 2) + lr) * 64 + (s0b ^ 32);
  const unsigned char* b0 = Bb + (wc * 64 + lr) * 64 + s0b;
  const unsigned char* b1 = Bb + (wc * 64 + lr) * 64 + (s0b ^ 32);

  f32x4 acc[MF][4] = {};

  auto BODY = [&](int P) {  // P literal at call sites
    const int ao = P * ABUF;
    const int bo = P * 16384;
    long af[MF][2], bf[4][2];
    #pragma unroll
    for (int mi = 0; mi < MF; ++mi) {
      af[mi][0] = *reinterpret_cast<const long*>(a0 + ao + mi * 1024);
      af[mi][1] = *reinterpret_cast<const long*>(a1 + ao + mi * 1024);
    }
    #pragma unroll
    for (int n = 0; n < 4; ++n) {
      bf[n][0] = *reinterpret_cast<const long*>(b0 + bo + n * 1024);
      bf[n][1] = *reinterpret_cast<const long*>(b1 + bo + n * 1024);
    }
    #pragma unroll
    for (int kk = 0; kk < 2; ++kk)
      #pragma unroll
      for (int mi = 0; mi < MF; ++mi)
        #pragma unroll
        for (int n = 0; n < 4; ++n)
          acc[mi][n] = __builtin_amdgcn_mfma_f32_16x16x32_fp8_fp8(
              af[mi][kk], bf[n][kk], acc[mi][n], 0, 0, 0);
  };

  auto WAITV = [&]() {
    if (ALOADS + 2 == 4) asm volatile("s_waitcnt vmcnt(4)" ::: "memory");
    else                 asm volatile("s_waitcnt vmcnt(3)" ::: "memory");
  };

  const int NT = K >> 6;
  STAGE(0, 0); STAGE(1, 1);
  WAITV();
  BAR();

  for (int k = 0; k < NT; k += 2) {
    BODY(0);
    BAR();
    if (k + 2 < NT) { STAGE(0, k + 2); WAITV(); }
    else { asm volatile("s_waitcnt vmcnt(0)" ::: "memory"); }
    BAR();
    BODY(1);
    if (k + 2 < NT) {
      BAR();
      if (k + 3 < NT) { STAGE(1, k + 3); WAITV(); }
      else { asm volatile("s_waitcnt vmcnt(0)" ::: "memory"); }
      BAR();
    }
  }

  const int rg = q * 4;
  if (MODE == 0) {
    unsigned char* Co = (unsigned char*)Cp + (size_t)z * sC;
    float* Dz = denom + (size_t)z * sDen;
    #pragma unroll
    for (int m = 0; m < MF; ++m) {
      float ev[4][4];
      #pragma unroll
      for (int n = 0; n < 4; ++n) {
        const int col = by * 256 + wc * 64 + n * 16 + lr;
        #pragma unroll
        for (int r = 0; r < 4; ++r) {
          int row = bx * MT + wr * (MT / 2) + m * 16 + rg + r;
          ev[n][r] = __expf(acc[m][n][r] * scale);
          Co[(size_t)row * ldc + col] = f2fp8(ev[n][r]);
        }
      }
      #pragma unroll
      for (int r = 0; r < 4; ++r) {
        float s = (ev[0][r] + ev[1][r]) + (ev[2][r] + ev[3][r]);
        s += __shfl_xor(s, 1); s += __shfl_xor(s, 2);
        s += __shfl_xor(s, 4); s += __shfl_xor(s, 8);
        if (lr == 0) {
          int row = bx * MT + wr * (MT / 2) + m * 16 + rg + r;
          atomicAdd(&Dz[row], s);
        }
      }
    }
  } else {
    float* Co = (float*)Cp + (size_t)z * sC;
    const float* Rs = resid + (size_t)z * sR;
    const float* Dz = denom + (size_t)z * sDen;
    #pragma unroll
    for (int n = 0; n < 4; ++n) {
      const int col = by * 256 + wc * 64 + n * 16 + lr;
      const float dinv = 1.0f / Dz[col];
      #pragma unroll
      for (int m = 0; m < MF; ++m)
        #pragma unroll
        for (int r = 0; r < 4; ++r) {
          int row = bx * MT + wr * (MT / 2) + m * 16 + rg + r;
          size_t idx = (size_t)row * ldc + col;
          Co[idx] = acc[m][n][r] * dinv + bias[row] + Rs[idx];
        }
    }
  }
}

extern "C" void kernel_launch(void* const* d_in, const int* in_sizes, int n_in,
                              void* d_out, int out_size, void* d_ws, size_t ws_size,
                              hipStream_t stream) {
  const float* x  = (const float*)d_in[0];
  const float* wq = (const float*)d_in[1];
  const float* bq = (const float*)d_in[2];
  const float* wk = (const float*)d_in[3];
  const float* bk = (const float*)d_in[4];
  const float* wv = (const float*)d_in[5];
  const float* bv = (const float*)d_in[6];
  const float* wp = (const float*)d_in[7];
  const float* bp = (const float*)d_in[8];
  float* out = (float*)d_out;
  char* ws = (char*)d_ws;
  const size_t MB = 1024 * 1024;
  unsigned short* Wq  = (unsigned short*)(ws + 0);
  unsigned short* Wk  = (unsigned short*)(ws + 512 * 1024);
  unsigned short* Wv  = (unsigned short*)(ws + 1 * MB);
  unsigned short* Wp  = (unsigned short*)(ws + MB + 512 * 1024);
  unsigned short* Xt  = (unsigned short*)(ws + 2 * MB);   // [B,N,C] bf16
  unsigned char*  Qb8 = (unsigned char*)(ws + 18 * MB);   // [B,N,C] fp8
  unsigned char*  Kb8 = (unsigned char*)(ws + 26 * MB);   // [B,N,C] fp8
  unsigned short* Vb  = (unsigned short*)(ws + 34 * MB);  // [B,N,C] bf16
  unsigned char*  PVt = (unsigned char*)(ws + 50 * MB);   // [B,C,N] fp8
  float* denom = (float*)(ws + 58 * MB);                  // [B,N] f32
  unsigned char*  P8  = (unsigned char*)(ws + 59 * MB);   // E fp8 [N,N] x (1|4)
  const long NCe = (long)N_DIM * C_DIM;
  const long NNe = (long)N_DIM * N_DIM;
  const long PVe = (long)C_DIM * N_DIM;
  const float rs = 0.044194173824159216f;  // 1/sqrt(512)
  const bool big = ws_size >= 59 * MB + 4 * (size_t)N_DIM * N_DIM;

  cvt_weights<<<dim3((C_DIM * C_DIM + 255) / 256), 256, 0, stream>>>(
      wq, wk, wv, wp, Wq, Wk, Wv, Wp);
  transpose_x<<<dim3(N_DIM / 32, C_DIM / 32, B_DIM), dim3(32, 8), 0, stream>>>(x, Xt);
  gemm_qkv<<<dim3(32, 4, 12), 256, 0, stream>>>(
      Xt, Wq, Wk, Wv, bq, bk, bv, Qb8, Kb8, Vb);
  gemm_pvt<<<dim3(4, 32, 4), 256, 0, stream>>>(Wp, Vb, PVt);
  zero_buf<<<dim3(B_DIM * N_DIM / 256), 256, 0, stream>>>(denom, B_DIM * N_DIM);

  if (big) {
    // E = exp(rs * Q.K^T) (fp8); denom[n] += rowsum (f32)
    gemm_p<8, 0, 16, 16><<<dim3(16, 16, 4), 512, 0, stream>>>(
        Qb8, NCe, Kb8, NCe, P8, NNe, C_DIM, C_DIM, C_DIM, N_DIM, rs,
        nullptr, denom, N_DIM, nullptr, 0);
    // out[o,n] = (sum_j PVt[o,j] E[n,j]) / denom[n] + bp[o] + x[o,n]
    gemm_p<4, 1, 4, 16><<<dim3(4, 16, 4), 512, 0, stream>>>(
        PVt, PVe, P8, NNe, out, NCe, N_DIM, N_DIM, N_DIM, N_DIM, 1.0f,
        bp, denom, N_DIM, x, NCe);
  } else {
    for (int b = 0; b < B_DIM; ++b) {
      gemm_p<8, 0, 16, 16><<<dim3(16, 16, 1), 512, 0, stream>>>(
          Qb8 + (size_t)b * NCe, 0, Kb8 + (size_t)b * NCe, 0, P8, 0,
          C_DIM, C_DIM, C_DIM, N_DIM, rs, nullptr, denom + (size_t)b * N_DIM, 0,
          nullptr, 0);
      gemm_p<4, 1, 4, 16><<<dim3(4, 16, 1), 512, 0, stream>>>(
          PVt + (size_t)b * PVe, 0, P8, 0, (void*)(out + (size_t)b * NCe), 0,
          N_DIM, N_DIM, N_DIM, N_DIM, 1.0f, bp, denom + (size_t)b * N_DIM, 0,
          x + (size_t)b * NCe, 0);
    }
  }
}

// Round 12
// 181.605 us; speedup vs baseline: 1.3635x; 1.3635x over previous
//
#include <hip/hip_runtime.h>
#include <hip/hip_bf16.h>
#include <stdint.h>

// B=4, C=512, H=W=64 -> N=4096. Channel-first x [B,C,N].
#define C_DIM 512
#define N_DIM 4096
#define B_DIM 4

typedef __bf16 bf16x8 __attribute__((ext_vector_type(8)));
typedef float f32x4 __attribute__((ext_vector_type(4)));
typedef int i32x8 __attribute__((ext_vector_type(8)));
#define AS1 __attribute__((address_space(1)))
#define AS3 __attribute__((address_space(3)))

static __device__ __forceinline__ unsigned short f2bf(float x) {
  unsigned u = __float_as_uint(x);
  unsigned r = (u + 0x7fffu + ((u >> 16) & 1u)) >> 16;
  return (unsigned short)r;
}
static __device__ __forceinline__ unsigned char f2fp8(float x) {
  return (unsigned char)__builtin_amdgcn_cvt_pk_fp8_f32(x, x, 0, false);
}

__global__ __launch_bounds__(256) void cvt_weights(
    const float* __restrict__ w0, const float* __restrict__ w1,
    const float* __restrict__ w2, const float* __restrict__ w3,
    unsigned short* __restrict__ o0, unsigned short* __restrict__ o1,
    unsigned short* __restrict__ o2, unsigned short* __restrict__ o3) {
  int i = blockIdx.x * blockDim.x + threadIdx.x;
  if (i < C_DIM * C_DIM) {
    o0[i] = f2bf(w0[i]); o1[i] = f2bf(w1[i]);
    o2[i] = f2bf(w2[i]); o3[i] = f2bf(w3[i]);
  }
}

// x [B,C,N] f32 -> Xt [B,N,C] bf16
__global__ __launch_bounds__(256) void transpose_x(
    const float* __restrict__ x, unsigned short* __restrict__ Xt) {
  __shared__ float t[32][33];
  const int b = blockIdx.z;
  const float* xb = x + (size_t)b * C_DIM * N_DIM;
  unsigned short* xtb = Xt + (size_t)b * N_DIM * C_DIM;
  const int n0 = blockIdx.x * 32, c0 = blockIdx.y * 32;
  const int tx = threadIdx.x, ty = threadIdx.y;
  #pragma unroll
  for (int i = ty; i < 32; i += 8)
    t[i][tx] = xb[(size_t)(c0 + i) * N_DIM + n0 + tx];
  __syncthreads();
  #pragma unroll
  for (int i = ty; i < 32; i += 8)
    xtb[(size_t)(n0 + i) * C_DIM + c0 + tx] = f2bf(t[tx][i]);
}

__global__ __launch_bounds__(256) void zero_buf(float* __restrict__ p, int n) {
  int i = blockIdx.x * 256 + threadIdx.x;
  if (i < n) p[i] = 0.f;
}

// ---------------- 128^2-tile 2-phase NT GEMM body (bf16 inputs) ------------
// C[i,j] = sum_k A[i,k]B[j,k]; BIAS: 0 none, 1 +bias[col].
// OUT8: 1 -> fp8 e4m3 output, 0 -> bf16 output.
template<int BIAS, int OUT8>
__device__ __forceinline__ void gemm128_body(
    unsigned short* As, unsigned short* Bs,
    const unsigned short* __restrict__ A, const unsigned short* __restrict__ B,
    void* __restrict__ Cv, int K, int ldc,
    const float* __restrict__ bias, int bx, int by) {
  const int tid = threadIdx.x;
  const int wid = tid >> 6, lane = tid & 63;
  const int wm = (wid >> 1) * 64, wn = (wid & 1) * 64;
  f32x4 acc[4][4] = {};
  const size_t rowA0 = (size_t)bx * 128;
  const size_t rowB0 = (size_t)by * 128;
  const int sgrp = wid * 2;
  const int r0 = (sgrp * 64 + lane) >> 2;
  const int r1 = ((sgrp + 1) * 64 + lane) >> 2;
  const int cc = ((lane & 3) ^ ((lane >> 3) & 3)) * 8;
  const int lr = lane & 15;
  const int koff = (((lane >> 4) ^ ((lr >> 1) & 3))) * 8;

  for (int k0 = 0; k0 < K; k0 += 32) {
    __syncthreads();
    __builtin_amdgcn_global_load_lds(
        (const AS1 void*)(A + (rowA0 + r0) * K + k0 + cc),
        (AS3 void*)(As + sgrp * 512), 16, 0, 0);
    __builtin_amdgcn_global_load_lds(
        (const AS1 void*)(A + (rowA0 + r1) * K + k0 + cc),
        (AS3 void*)(As + (sgrp + 1) * 512), 16, 0, 0);
    __builtin_amdgcn_global_load_lds(
        (const AS1 void*)(B + (rowB0 + r0) * K + k0 + cc),
        (AS3 void*)(Bs + sgrp * 512), 16, 0, 0);
    __builtin_amdgcn_global_load_lds(
        (const AS1 void*)(B + (rowB0 + r1) * K + k0 + cc),
        (AS3 void*)(Bs + (sgrp + 1) * 512), 16, 0, 0);
    __syncthreads();
    bf16x8 af[4], bf[4];
    #pragma unroll
    for (int m = 0; m < 4; ++m)
      af[m] = *reinterpret_cast<const bf16x8*>(&As[(wm + m * 16 + lr) * 32 + koff]);
    #pragma unroll
    for (int n = 0; n < 4; ++n)
      bf[n] = *reinterpret_cast<const bf16x8*>(&Bs[(wn + n * 16 + lr) * 32 + koff]);
    #pragma unroll
    for (int m = 0; m < 4; ++m)
      #pragma unroll
      for (int n = 0; n < 4; ++n)
        acc[m][n] = __builtin_amdgcn_mfma_f32_16x16x32_bf16(af[m], bf[n], acc[m][n], 0, 0, 0);
  }

  const int rg = (lane >> 4) * 4;
  #pragma unroll
  for (int m = 0; m < 4; ++m) {
    #pragma unroll
    for (int n = 0; n < 4; ++n) {
      const int col = (int)rowB0 + wn + n * 16 + lr;
      #pragma unroll
      for (int r = 0; r < 4; ++r) {
        int row = (int)rowA0 + wm + m * 16 + rg + r;
        float v = acc[m][n][r];
        if (BIAS == 1) v += bias[col];
        if (OUT8)
          ((unsigned char*)Cv)[(size_t)row * ldc + col] = f2fp8(v);
        else
          ((unsigned short*)Cv)[(size_t)row * ldc + col] = f2bf(v);
      }
    }
  }
}

// merged Q,K,V projections: grid (32, 4, 12); z = wsel + 3*batch
// Q,K written as fp8 e4m3; V as bf16 (consumed by gemm_pvt).
__global__ __launch_bounds__(256, 2) void gemm_qkv(
    const unsigned short* __restrict__ Xt,
    const unsigned short* __restrict__ Wq, const unsigned short* __restrict__ Wk,
    const unsigned short* __restrict__ Wv,
    const float* __restrict__ bq, const float* __restrict__ bk,
    const float* __restrict__ bv,
    unsigned char* __restrict__ Qb, unsigned char* __restrict__ Kb,
    unsigned short* __restrict__ Vb) {
  __shared__ unsigned short As[4096], Bs[4096];
  const long NCe = (long)N_DIM * C_DIM;
  const int z = blockIdx.z;
  const int wsel = z % 3, bat = z / 3;
  const unsigned short* Xz = Xt + (size_t)bat * NCe;
  if (wsel == 0) {
    gemm128_body<1, 1>(As, Bs, Xz, Wq, Qb + (size_t)bat * NCe, C_DIM, C_DIM,
                       bq, blockIdx.x, blockIdx.y);
  } else if (wsel == 1) {
    gemm128_body<1, 1>(As, Bs, Xz, Wk, Kb + (size_t)bat * NCe, C_DIM, C_DIM,
                       bk, blockIdx.x, blockIdx.y);
  } else {
    gemm128_body<1, 0>(As, Bs, Xz, Wv, Vb + (size_t)bat * NCe, C_DIM, C_DIM,
                       bv, blockIdx.x, blockIdx.y);
  }
}

// PVt[o,j] = sum_c Wp[o,c] V[j,c] -> fp8; grid (4, 32, 4)
__global__ __launch_bounds__(256, 2) void gemm_pvt(
    const unsigned short* __restrict__ Wp, const unsigned short* __restrict__ Vb,
    unsigned char* __restrict__ PVt) {
  __shared__ unsigned short As[4096], Bs[4096];
  const long NCe = (long)N_DIM * C_DIM;
  const long PVe = (long)C_DIM * N_DIM;
  const int z = blockIdx.z;
  gemm128_body<0, 1>(As, Bs, Wp, Vb + (size_t)z * NCe, PVt + (size_t)z * PVe,
                     C_DIM, N_DIM, nullptr, blockIdx.x, blockIdx.y);
}

// ---------------- MX-fp8 128^2-tile NT GEMM (m97 structure, K-step 128) -----
// A,B fp8 e4m3 row-major NT. 256 thr = 4 waves (2x2), per-wave 64x64,
// acc[4][4]. mfma_scale_f32_16x16x128_f8f6f4 with scale=1.0 (e8m0 127):
// exact fp8 math at 2x bf16 MFMA rate (m148 ladder: 1628 TF in this
// structure). Single-buffered 2-phase: sync; stage(8 gload_lds); sync
// (compiler drains vmcnt(0)); compute. LDS 32 KB -> 4-5 blocks/CU (m114
// cross-block overlap). fp8 row = 128 B = full bank period: proven 8-slot
// XOR swizzle p ^ (r&7), conflict-free (consecutive-8-lane rule, R8: 0).
// A-frag: lane l holds rows l&15, k = (l>>4)*32 .. +31 (two b128 reads).
// MODE 0: store fp8 exp(scale*acc); f32 rowsums -> atomicAdd denom[row].
// MODE 1: store f32 acc/denom[col] + bias[row] + resid  (final output).
template<int MODE, int GX, int GY>
__global__ __launch_bounds__(256, 3) void gemm_mx(
    const unsigned char* __restrict__ A, long sA,
    const unsigned char* __restrict__ B, long sB,
    void* __restrict__ Cp, long sC,
    int K, int lda, int ldb, int ldc, float scale,
    const float* __restrict__ bias,
    float* __restrict__ denom, long sDen,
    const float* __restrict__ resid, long sR) {
  __shared__ unsigned char Asm[16384], Bsm[16384];

  // XCD-aware bijective block swizzle (nwg % 8 == 0 at all call sites)
  int flat = blockIdx.x + GX * (blockIdx.y + GY * blockIdx.z);
  const int nwg = GX * GY * gridDim.z;
  flat = (flat & 7) * (nwg >> 3) + (flat >> 3);
  const int bx = flat & (GX - 1);
  const int by = (flat / GX) & (GY - 1);
  const int z  = flat / (GX * GY);

  const unsigned char* Ag = A + (size_t)z * sA + (size_t)bx * 128 * lda;
  const unsigned char* Bg = B + (size_t)z * sB + (size_t)by * 128 * ldb;
  const int tid = threadIdx.x;
  const int wid = tid >> 6, lane = tid & 63;
  const int wm = (wid >> 1) * 64, wn = (wid & 1) * 64;
  const int lr = lane & 15, q = lane >> 4;
  // staging: 8 threads/row (128 B); phys slot lane&7 carries global slot
  // (lane&7) ^ (rowlocal&7), rowlocal&7 = (lane>>3)&7... rows per instr = 8.
  const int g16 = ((lane & 7) ^ ((lane >> 3) & 7)) * 16;
  // read: 32 B at k=q*32 -> global slots 2q, 2q+1; phys = slot ^ (row&7),
  // row&7 == lr&7 for fragment rows.
  const int rl = lr & 7;
  const int rb0 = (((2 * q) ^ rl)) * 16;
  const int rb1 = (((2 * q + 1) ^ rl)) * 16;

  f32x4 acc[4][4] = {};
  const int NT = K >> 7;

  for (int t = 0; t < NT; ++t) {
    __syncthreads();
    const int k0 = t << 7;
    #pragma unroll
    for (int i = 0; i < 4; ++i) {
      const int rr = (i * 4 + wid) * 8 + (lane >> 3);
      __builtin_amdgcn_global_load_lds(
          (const AS1 void*)(Ag + (size_t)rr * lda + k0 + g16),
          (AS3 void*)(Asm + (i * 4 + wid) * 1024), 16, 0, 0);
      __builtin_amdgcn_global_load_lds(
          (const AS1 void*)(Bg + (size_t)rr * ldb + k0 + g16),
          (AS3 void*)(Bsm + (i * 4 + wid) * 1024), 16, 0, 0);
    }
    __syncthreads();  // compiler emits s_waitcnt vmcnt(0) before barrier

    i32x8 bf[4];
    #pragma unroll
    for (int n = 0; n < 4; ++n) {
      const unsigned char* rp = Bsm + (wn + n * 16 + lr) * 128;
      uint4 lo = *reinterpret_cast<const uint4*>(rp + rb0);
      uint4 hi = *reinterpret_cast<const uint4*>(rp + rb1);
      i32x8 v;
      v[0] = lo.x; v[1] = lo.y; v[2] = lo.z; v[3] = lo.w;
      v[4] = hi.x; v[5] = hi.y; v[6] = hi.z; v[7] = hi.w;
      bf[n] = v;
    }
    #pragma unroll
    for (int mi = 0; mi < 4; ++mi) {
      const unsigned char* rp = Asm + (wm + mi * 16 + lr) * 128;
      uint4 lo = *reinterpret_cast<const uint4*>(rp + rb0);
      uint4 hi = *reinterpret_cast<const uint4*>(rp + rb1);
      i32x8 af;
      af[0] = lo.x; af[1] = lo.y; af[2] = lo.z; af[3] = lo.w;
      af[4] = hi.x; af[5] = hi.y; af[6] = hi.z; af[7] = hi.w;
      #pragma unroll
      for (int n = 0; n < 4; ++n)
        acc[mi][n] = __builtin_amdgcn_mfma_scale_f32_16x16x128_f8f6f4(
            af, bf[n], acc[mi][n], 0, 0, 0, 127, 0, 127);
    }
  }

  const int rg = q * 4;
  if (MODE == 0) {
    unsigned char* Co = (unsigned char*)Cp + (size_t)z * sC;
    float* Dz = denom + (size_t)z * sDen;
    #pragma unroll
    for (int m = 0; m < 4; ++m) {
      float ev[4][4];
      #pragma unroll
      for (int n = 0; n < 4; ++n) {
        const int col = by * 128 + wn + n * 16 + lr;
        #pragma unroll
        for (int r = 0; r < 4; ++r) {
          int row = bx * 128 + wm + m * 16 + rg + r;
          ev[n][r] = __expf(acc[m][n][r] * scale);
          Co[(size_t)row * ldc + col] = f2fp8(ev[n][r]);
        }
      }
      #pragma unroll
      for (int r = 0; r < 4; ++r) {
        float s = (ev[0][r] + ev[1][r]) + (ev[2][r] + ev[3][r]);
        s += __shfl_xor(s, 1); s += __shfl_xor(s, 2);
        s += __shfl_xor(s, 4); s += __shfl_xor(s, 8);
        if (lr == 0) {
          int row = bx * 128 + wm + m * 16 + rg + r;
          atomicAdd(&Dz[row], s);
        }
      }
    }
  } else {
    float* Co = (float*)Cp + (size_t)z * sC;
    const float* Rs = resid + (size_t)z * sR;
    const float* Dz = denom + (size_t)z * sDen;
    #pragma unroll
    for (int n = 0; n < 4; ++n) {
      const int col = by * 128 + wn + n * 16 + lr;
      const float dinv = 1.0f / Dz[col];
      #pragma unroll
      for (int m = 0; m < 4; ++m)
        #pragma unroll
        for (int r = 0; r < 4; ++r) {
          int row = bx * 128 + wm + m * 16 + rg + r;
          size_t idx = (size_t)row * ldc + col;
          Co[idx] = acc[m][n][r] * dinv + bias[row] + Rs[idx];
        }
    }
  }
}

extern "C" void kernel_launch(void* const* d_in, const int* in_sizes, int n_in,
                              void* d_out, int out_size, void* d_ws, size_t ws_size,
                              hipStream_t stream) {
  const float* x  = (const float*)d_in[0];
  const float* wq = (const float*)d_in[1];
  const float* bq = (const float*)d_in[2];
  const float* wk = (const float*)d_in[3];
  const float* bk = (const float*)d_in[4];
  const float* wv = (const float*)d_in[5];
  const float* bv = (const float*)d_in[6];
  const float* wp = (const float*)d_in[7];
  const float* bp = (const float*)d_in[8];
  float* out = (float*)d_out;
  char* ws = (char*)d_ws;
  const size_t MB = 1024 * 1024;
  unsigned short* Wq  = (unsigned short*)(ws + 0);
  unsigned short* Wk  = (unsigned short*)(ws + 512 * 1024);
  unsigned short* Wv  = (unsigned short*)(ws + 1 * MB);
  unsigned short* Wp  = (unsigned short*)(ws + MB + 512 * 1024);
  unsigned short* Xt  = (unsigned short*)(ws + 2 * MB);   // [B,N,C] bf16
  unsigned char*  Qb8 = (unsigned char*)(ws + 18 * MB);   // [B,N,C] fp8
  unsigned char*  Kb8 = (unsigned char*)(ws + 26 * MB);   // [B,N,C] fp8
  unsigned short* Vb  = (unsigned short*)(ws + 34 * MB);  // [B,N,C] bf16
  unsigned char*  PVt = (unsigned char*)(ws + 50 * MB);   // [B,C,N] fp8
  float* denom = (float*)(ws + 58 * MB);                  // [B,N] f32
  unsigned char*  P8  = (unsigned char*)(ws + 59 * MB);   // E fp8 [N,N] x (1|4)
  const long NCe = (long)N_DIM * C_DIM;
  const long NNe = (long)N_DIM * N_DIM;
  const long PVe = (long)C_DIM * N_DIM;
  const float rs = 0.044194173824159216f;  // 1/sqrt(512)
  const bool big = ws_size >= 59 * MB + 4 * (size_t)N_DIM * N_DIM;

  cvt_weights<<<dim3((C_DIM * C_DIM + 255) / 256), 256, 0, stream>>>(
      wq, wk, wv, wp, Wq, Wk, Wv, Wp);
  transpose_x<<<dim3(N_DIM / 32, C_DIM / 32, B_DIM), dim3(32, 8), 0, stream>>>(x, Xt);
  gemm_qkv<<<dim3(32, 4, 12), 256, 0, stream>>>(
      Xt, Wq, Wk, Wv, bq, bk, bv, Qb8, Kb8, Vb);
  gemm_pvt<<<dim3(4, 32, 4), 256, 0, stream>>>(Wp, Vb, PVt);
  zero_buf<<<dim3(B_DIM * N_DIM / 256), 256, 0, stream>>>(denom, B_DIM * N_DIM);

  if (big) {
    // E = exp(rs * Q.K^T) (fp8); denom[n] += rowsum (f32, pre-rounding)
    gemm_mx<0, 32, 32><<<dim3(32, 32, 4), 256, 0, stream>>>(
        Qb8, NCe, Kb8, NCe, P8, NNe, C_DIM, C_DIM, C_DIM, N_DIM, rs,
        nullptr, denom, N_DIM, nullptr, 0);
    // out[o,n] = (sum_j PVt[o,j] E[n,j]) / denom[n] + bp[o] + x[o,n]
    gemm_mx<1, 4, 32><<<dim3(4, 32, 4), 256, 0, stream>>>(
        PVt, PVe, P8, NNe, out, NCe, N_DIM, N_DIM, N_DIM, N_DIM, 1.0f,
        bp, denom, N_DIM, x, NCe);
  } else {
    for (int b = 0; b < B_DIM; ++b) {
      gemm_mx<0, 32, 32><<<dim3(32, 32, 1), 256, 0, stream>>>(
          Qb8 + (size_t)b * NCe, 0, Kb8 + (size_t)b * NCe, 0, P8, 0,
          C_DIM, C_DIM, C_DIM, N_DIM, rs, nullptr, denom + (size_t)b * N_DIM, 0,
          nullptr, 0);
      gemm_mx<1, 4, 32><<<dim3(4, 32, 1), 256, 0, stream>>>(
          PVt + (size_t)b * PVe, 0, P8, 0, (void*)(out + (size_t)b * NCe), 0,
          N_DIM, N_DIM, N_DIM, N_DIM, 1.0f, bp, denom + (size_t)b * N_DIM, 0,
          x + (size_t)b * NCe, 0);
    }
  }
}